// Round 7
// baseline (128.028 us; speedup 1.0000x reference)
//
#include <hip/hip_runtime.h>
#include <hip/hip_cooperative_groups.h>
#include <math.h>

namespace cg = cooperative_groups;

#define NPTS   8192
#define BATCH  2
#define KNN    20
#define COUT   64
#define NCLASS 40
#define NBKT   32
#define BCAP   512   // mean 256, sd ~15.7 -> 512 = +16 sigma, never overflows

// Gaussian quantile splitters s[i] = Phi^-1((i+1)/32). Only affect load
// balance, never correctness (any splitters give an exact sort).
__device__ __constant__ float SPLIT[NBKT - 1] = {
    -1.86273f, -1.53412f, -1.31801f, -1.15035f, -1.00999f, -0.88715f,
    -0.77642f, -0.67449f, -0.57913f, -0.48878f, -0.40225f, -0.31864f,
    -0.23720f, -0.15731f, -0.07841f,  0.00000f,  0.07841f,  0.15731f,
     0.23720f,  0.31864f,  0.40225f,  0.48878f,  0.57913f,  0.67449f,
     0.77642f,  0.88715f,  1.00999f,  1.15035f,  1.31801f,  1.53412f,
     1.86273f };

// compare-exchange: a=lower index, b=upper index
__device__ __forceinline__ void ce(float& a, float& b, bool up) {
    const float lo = fminf(a, b), hi = fmaxf(a, b);
    a = up ? lo : hi;
    b = up ? hi : lo;
}

// ---------------------------------------------------------------------------
// ONE cooperative dispatch, 64 blocks x 256 threads. Block bi = (batch, sub):
//   Phase A: samplesort bucket sub (round-6 proven): 256-thread filter scan
//            with below-count (= exact output offset), wave-0 512-elem
//            register bitonic (zero LDS/barriers in the sort), write xs.
//   grid.sync()
//   Phase B: two-pointer 20-NN window + folded conv/BN/relu + max/sum pooling
//            on chunk sub (round-2/6 proven logic), partials to ws.
//   grid.sync()
//   Phase C: block 0 reduces 64 partials + linear head.
// ---------------------------------------------------------------------------
__global__ __launch_bounds__(256) void fused_coop(
        const float* __restrict__ x,
        const float* __restrict__ conv_w,
        const float* __restrict__ bn_g,
        const float* __restrict__ bn_b,
        const float* __restrict__ bn_m,
        const float* __restrict__ bn_v,
        const float* __restrict__ lin_w,
        float* __restrict__ xs,
        float* __restrict__ partM,
        float* __restrict__ partS,
        float* __restrict__ out) {
    cg::grid_group grid = cg::this_grid();

    const int t   = threadIdx.x;
    const int bi  = blockIdx.x;
    const int b   = bi >> 5;                    // batch
    const int sub = bi & 31;                    // bucket / chunk id

    // ---------------- Phase A: samplesort bucket (b, sub) --------------------
    __shared__ float buf[BCAP];
    __shared__ int   cnt_s;
    __shared__ int   bel[4];
    if (t == 0) cnt_s = 0;
    __syncthreads();

    {
        const float lo = (sub == 0)        ? -INFINITY : SPLIT[sub - 1];
        const float hi = (sub == NBKT - 1) ?  INFINITY : SPLIT[sub];
        int below = 0;
        const float4* xv = (const float4*)(x + b * NPTS);
        #pragma unroll
        for (int it = 0; it < 8; ++it) {
            const float4 a = xv[it * 256 + t];
            const float vals[4] = {a.x, a.y, a.z, a.w};
            #pragma unroll
            for (int q = 0; q < 4; ++q) {
                const float v = vals[q];
                below += (v < lo) ? 1 : 0;
                if (v >= lo && v < hi) {
                    const int pos = atomicAdd(&cnt_s, 1);
                    if (pos < BCAP) buf[pos] = v;   // guard: statistically never
                }
            }
        }
        #pragma unroll
        for (int s = 1; s <= 32; s <<= 1) below += __shfl_xor(below, s, 64);
        if ((t & 63) == 0) bel[t >> 6] = below;
    }
    __syncthreads();                            // buf + bel visible

    if (t < 64) {                               // wave 0 sorts the bucket
        const int lane = t;
        const int start = bel[0] + bel[1] + bel[2] + bel[3];  // exact offset
        const int n = min(cnt_s, BCAP);

        float v[8];
        #pragma unroll
        for (int q = 0; q < 8; ++q) {
            const int j = lane * 8 + q;
            v[q] = (j < n) ? buf[j] : INFINITY;
        }
        // k=2
        ce(v[0],v[1],true);  ce(v[2],v[3],false); ce(v[4],v[5],true);  ce(v[6],v[7],false);
        // k=4
        ce(v[0],v[2],true);  ce(v[1],v[3],true);  ce(v[4],v[6],false); ce(v[5],v[7],false);
        ce(v[0],v[1],true);  ce(v[2],v[3],true);  ce(v[4],v[5],false); ce(v[6],v[7],false);
        // k=8 (direction uniform per thread)
        {
            const bool u8 = ((lane & 1) == 0);
            ce(v[0],v[4],u8); ce(v[1],v[5],u8); ce(v[2],v[6],u8); ce(v[3],v[7],u8);
            ce(v[0],v[2],u8); ce(v[1],v[3],u8); ce(v[4],v[6],u8); ce(v[5],v[7],u8);
            ce(v[0],v[1],u8); ce(v[2],v[3],u8); ce(v[4],v[5],u8); ce(v[6],v[7],u8);
        }
        // k=16..512: shuffle phases (lane offset 1..32, in-wave)
        for (int k = 16; k <= 512; k <<= 1) {
            const bool up = (lane & (k >> 3)) == 0;
            for (int j = (k >> 1) < 256 ? (k >> 1) : 256; j >= 8; j >>= 1) {
                const int lm = j >> 3;
                const bool tmin = up ^ ((lane & lm) != 0);
                #pragma unroll
                for (int q = 0; q < 8; ++q) {
                    const float o = __shfl_xor(v[q], lm, 64);
                    v[q] = tmin ? fminf(v[q], o) : fmaxf(v[q], o);
                }
            }
            ce(v[0],v[4],up); ce(v[1],v[5],up); ce(v[2],v[6],up); ce(v[3],v[7],up);
            ce(v[0],v[2],up); ce(v[1],v[3],up); ce(v[4],v[6],up); ce(v[5],v[7],up);
            ce(v[0],v[1],up); ce(v[2],v[3],up); ce(v[4],v[5],up); ce(v[6],v[7],up);
        }

        float* xb = xs + b * NPTS + start;
        #pragma unroll
        for (int q = 0; q < 8; ++q) {
            const int j = lane * 8 + q;
            if (j < n) xb[j] = v[q];
        }
    }

    __threadfence();                            // xs visible device-wide
    grid.sync();

    // ---------------- Phase B: knn + conv/BN/relu + pooling on chunk ---------
    const int base = sub * 256;
    const int off  = base - 32;                 // ls[i] <-> global index off+i
    const float* xbr = xs + b * NPTS;

    __shared__ float ls[320];                   // [base-32, base+288)
    {
        const int gi = off + t;
        ls[t] = (gi >= 0 && gi < NPTS) ? xbr[gi] : 0.0f;
        if (t < 64) {
            const int gi2 = base + 224 + t;
            ls[256 + t] = (gi2 < NPTS) ? xbr[gi2] : 0.0f;
        }
    }
    __syncthreads();

    const int p = base + t;
    const float xn = ls[t + 32];
    int l = p, r = p;
    #pragma unroll
    for (int st = 0; st < KNN - 1; ++st) {
        float pdl = -INFINITY, pdr = -INFINITY;
        if (l > 0) {
            const float xl = ls[l - 1 - off];
            pdl = 2.0f * xn * xl - xn * xn - xl * xl;   // reference pd formula
        }
        if (r < NPTS - 1) {
            const float xr = ls[r + 1 - off];
            pdr = 2.0f * xn * xr - xn * xn - xr * xr;
        }
        if (pdl >= pdr) --l; else ++r;
    }

    __shared__ float sxp[256], smin[256], smax[256];
    sxp[t] = xn; smin[t] = ls[l - off]; smax[t] = ls[r - off];
    __syncthreads();

    {
        const int c = t & 63, q = t >> 6;
        const float w0 = conv_w[2 * c];
        const float w1 = conv_w[2 * c + 1];
        const float sc = bn_g[c] / sqrtf(bn_v[c] + 1e-5f);
        const float A  = sc * w0;
        const float Bc = sc * (w1 - w0);
        const float bias = bn_b[c] - bn_m[c] * sc;
        const float* warr = (A >= 0.0f) ? smax : smin;  // relu+max monotonicity

        float vmax = 0.0f, vsum = 0.0f;
        const int bse = q * 64;
        #pragma unroll 8
        for (int i = 0; i < 64; ++i) {
            const int pp = bse + i;
            float h = A * warr[pp] + Bc * sxp[pp] + bias;
            h = fmaxf(h, 0.0f);
            vmax = fmaxf(vmax, h);
            vsum += h;
        }

        __shared__ float pmax[256], psum[256];
        pmax[t] = vmax; psum[t] = vsum;
        __syncthreads();
        if (t < 64) {
            const float m  = fmaxf(fmaxf(pmax[t], pmax[t + 64]),
                                   fmaxf(pmax[t + 128], pmax[t + 192]));
            const float su = psum[t] + psum[t + 64] + psum[t + 128] + psum[t + 192];
            partM[(b * 32 + sub) * COUT + t] = m;
            partS[(b * 32 + sub) * COUT + t] = su;
        }
    }

    __threadfence();                            // partials visible device-wide
    grid.sync();

    // ---------------- Phase C: block 0 reduces partials + head ---------------
    if (bi == 0) {
        __shared__ float pool[BATCH][2 * COUT];
        if (t < 128) {
            const int bb = t >> 6, cc = t & 63;
            float m = 0.0f, s = 0.0f;
            #pragma unroll 8
            for (int ch = 0; ch < 32; ++ch) {
                m = fmaxf(m, partM[(bb * 32 + ch) * COUT + cc]);
                s += partS[(bb * 32 + ch) * COUT + cc];
            }
            pool[bb][cc]        = m;
            pool[bb][COUT + cc] = s * (1.0f / (float)NPTS);
        }
        __syncthreads();
        if (t < BATCH * NCLASS) {
            const int bb = t / NCLASS, j = t % NCLASS;
            const float* lw = lin_w + j * (2 * COUT);
            float acc = 0.0f;
            #pragma unroll
            for (int cc = 0; cc < 2 * COUT; ++cc) acc += pool[bb][cc] * lw[cc];
            out[bb * NCLASS + j] = acc;
        }
    }
}

extern "C" void kernel_launch(void* const* d_in, const int* in_sizes, int n_in,
                              void* d_out, int out_size, void* d_ws, size_t ws_size,
                              hipStream_t stream) {
    const float* x      = (const float*)d_in[0];   // (2, 8192)
    const float* conv_w = (const float*)d_in[1];   // (64, 2)
    const float* bn_g   = (const float*)d_in[2];
    const float* bn_b   = (const float*)d_in[3];
    const float* bn_m   = (const float*)d_in[4];
    const float* bn_v   = (const float*)d_in[5];
    const float* lin_w  = (const float*)d_in[6];   // (40, 128)
    float* out = (float*)d_out;                    // (2, 40) fp32

    float* xs    = (float*)d_ws;                   // 2*8192
    float* partM = xs + BATCH * NPTS;              // 2*32*64
    float* partS = partM + BATCH * 32 * COUT;      // 2*32*64

    void* args[] = {
        (void*)&x, (void*)&conv_w, (void*)&bn_g, (void*)&bn_b, (void*)&bn_m,
        (void*)&bn_v, (void*)&lin_w, (void*)&xs, (void*)&partM, (void*)&partS,
        (void*)&out
    };
    hipLaunchCooperativeKernel((const void*)fused_coop, dim3(BATCH * NBKT),
                               dim3(256), args, 0, stream);
}

// Round 8
// 96.943 us; speedup vs baseline: 1.3207x; 1.3207x over previous
//
#include <hip/hip_runtime.h>
#include <math.h>

#define NPTS   8192
#define BATCH  2
#define KNN    20
#define COUT   64
#define NCLASS 40
#define NBKT   32
#define BCAP   512   // bucket mean 256, sd ~15.7 -> 512 = +16 sigma, never overflows
#define SENT   0x5AFEC0DEF00D42AAULL

// Gaussian quantile splitters s[i] = Phi^-1((i+1)/32). Only affect load
// balance, never correctness (any splitters give an exact sort).
__device__ __constant__ float SPLIT[NBKT - 1] = {
    -1.86273f, -1.53412f, -1.31801f, -1.15035f, -1.00999f, -0.88715f,
    -0.77642f, -0.67449f, -0.57913f, -0.48878f, -0.40225f, -0.31864f,
    -0.23720f, -0.15731f, -0.07841f,  0.00000f,  0.07841f,  0.15731f,
     0.23720f,  0.31864f,  0.40225f,  0.48878f,  0.57913f,  0.67449f,
     0.77642f,  0.88715f,  1.00999f,  1.15035f,  1.31801f,  1.53412f,
     1.86273f };

// compare-exchange: a=lower index, b=upper index
__device__ __forceinline__ void ce(float& a, float& b, bool up) {
    const float lo = fminf(a, b), hi = fmaxf(a, b);
    a = up ? lo : hi;
    b = up ? hi : lo;
}

// Single-wave 512-element register bitonic (proven rounds 4-7): 8 elems/lane,
// j in {1,2,4} in-register, j in {8..256} via __shfl_xor. No LDS, no barriers.
__device__ __forceinline__ void sort512(int lane, const float* __restrict__ buf,
                                        int n, float* __restrict__ outp) {
    float v[8];
    #pragma unroll
    for (int q = 0; q < 8; ++q) {
        const int j = lane * 8 + q;
        v[q] = (j < n) ? buf[j] : INFINITY;
    }
    // k=2
    ce(v[0],v[1],true);  ce(v[2],v[3],false); ce(v[4],v[5],true);  ce(v[6],v[7],false);
    // k=4
    ce(v[0],v[2],true);  ce(v[1],v[3],true);  ce(v[4],v[6],false); ce(v[5],v[7],false);
    ce(v[0],v[1],true);  ce(v[2],v[3],true);  ce(v[4],v[5],false); ce(v[6],v[7],false);
    // k=8 (direction uniform per thread)
    {
        const bool u8 = ((lane & 1) == 0);
        ce(v[0],v[4],u8); ce(v[1],v[5],u8); ce(v[2],v[6],u8); ce(v[3],v[7],u8);
        ce(v[0],v[2],u8); ce(v[1],v[3],u8); ce(v[4],v[6],u8); ce(v[5],v[7],u8);
        ce(v[0],v[1],u8); ce(v[2],v[3],u8); ce(v[4],v[5],u8); ce(v[6],v[7],u8);
    }
    // k=16..512
    for (int k = 16; k <= 512; k <<= 1) {
        const bool up = (lane & (k >> 3)) == 0;
        for (int j = (k >> 1) < 256 ? (k >> 1) : 256; j >= 8; j >>= 1) {
            const int lm = j >> 3;
            const bool tmin = up ^ ((lane & lm) != 0);
            #pragma unroll
            for (int q = 0; q < 8; ++q) {
                const float o = __shfl_xor(v[q], lm, 64);
                v[q] = tmin ? fminf(v[q], o) : fmaxf(v[q], o);
            }
        }
        ce(v[0],v[4],up); ce(v[1],v[5],up); ce(v[2],v[6],up); ce(v[3],v[7],up);
        ce(v[0],v[2],up); ce(v[1],v[3],up); ce(v[4],v[6],up); ce(v[5],v[7],up);
        ce(v[0],v[1],up); ce(v[2],v[3],up); ce(v[4],v[5],up); ce(v[6],v[7],up);
    }
    #pragma unroll
    for (int q = 0; q < 8; ++q) {
        const int j = lane * 8 + q;
        if (j < n) outp[j] = v[q];
    }
}

// ---------------------------------------------------------------------------
// ONE regular dispatch, 64 blocks x 256 threads, NO grid-wide sync.
// Block (b,k) is fully self-sufficient for bucket k of batch b:
//   A: scan the whole row, filter buckets k-1,k,k+1 into LDS, count v<lo_k
//      (= exact global rank of bucket k's start; rounds 6/7 proven).
//   B: waves 0/1/2 register-sort the three buckets -> contiguous sorted LDS
//      region covering every 20-NN window of bucket k (window <=19 each way,
//      neighbor buckets ~256 wide).
//   C: two-pointer window per point (proven logic, global boundary checks).
//   D: folded conv+BN+relu, max/sum pooling over the bucket's points.
//   E: partials + sentinel flag (threadfence+atomicExch); blocks k==0 spin on
//      the 32 flags of their batch, reduce, run the linear head.
// ---------------------------------------------------------------------------
__global__ __launch_bounds__(256) void fused_kernel(
        const float* __restrict__ x,
        const float* __restrict__ conv_w,
        const float* __restrict__ bn_g,
        const float* __restrict__ bn_b,
        const float* __restrict__ bn_m,
        const float* __restrict__ bn_v,
        const float* __restrict__ lin_w,
        float* __restrict__ partM,
        float* __restrict__ partS,
        unsigned long long* __restrict__ flag,
        float* __restrict__ out) {
    __shared__ float bufL[BCAP], bufM[BCAP], bufR[BCAP];
    __shared__ float S[3 * BCAP];
    __shared__ float wmn[BCAP], wmx[BCAP];
    __shared__ float pmax[256], psum[256];
    __shared__ float pool[2 * COUT];
    __shared__ int   cntL, cntM, cntR;
    __shared__ int   bel[4];

    const int t    = threadIdx.x;
    const int lane = t & 63;
    const int wv   = t >> 6;
    const int b    = blockIdx.x >> 5;
    const int k    = blockIdx.x & 31;

    if (t == 0) { cntL = 0; cntM = 0; cntR = 0; }
    __syncthreads();

    // ---------------- Phase A: 3-range filter scan + below-count -------------
    const float bLlo = (k >= 2)  ? SPLIT[k - 2] : -INFINITY;
    const float lo   = (k >= 1)  ? SPLIT[k - 1] : -INFINITY;
    const float hi   = (k <= 30) ? SPLIT[k]     :  INFINITY;
    const float bRhi = (k <= 29) ? SPLIT[k + 1] :  INFINITY;
    const bool  hasL = (k >= 1), hasR = (k <= 30);

    int below = 0;
    {
        const float4* xv = (const float4*)(x + b * NPTS);
        #pragma unroll
        for (int it = 0; it < 8; ++it) {
            const float4 a = xv[it * 256 + t];
            const float vals[4] = {a.x, a.y, a.z, a.w};
            #pragma unroll
            for (int qq = 0; qq < 4; ++qq) {
                const float v = vals[qq];
                below += (v < lo) ? 1 : 0;
                if (v >= lo && v < hi) {
                    const int pos = atomicAdd(&cntM, 1);
                    if (pos < BCAP) bufM[pos] = v;       // statistically never
                } else if (hasL && v >= bLlo && v < lo) {
                    const int pos = atomicAdd(&cntL, 1);
                    if (pos < BCAP) bufL[pos] = v;
                } else if (hasR && v >= hi && v < bRhi) {
                    const int pos = atomicAdd(&cntR, 1);
                    if (pos < BCAP) bufR[pos] = v;
                }
            }
        }
    }
    #pragma unroll
    for (int s = 1; s <= 32; s <<= 1) below += __shfl_xor(below, s, 64);
    if (lane == 0) bel[wv] = below;
    __syncthreads();

    const int below_total = bel[0] + bel[1] + bel[2] + bel[3];
    const int nL = min(cntL, BCAP), nM = min(cntM, BCAP), nR = min(cntR, BCAP);

    // ---------------- Phase B: three single-wave register sorts --------------
    if (wv == 0)              sort512(lane, bufM, nM, S + nL);
    else if (wv == 1 && hasL) sort512(lane, bufL, nL, S);
    else if (wv == 2 && hasR) sort512(lane, bufR, nR, S + nL + nM);
    __syncthreads();

    // ---------------- Phase C: two-pointer 20-NN window ----------------------
    // S[i] holds global sorted index gofs+i; point lt of bucket k is S[nL+lt],
    // global p = below_total+lt. Window stays inside S (margins >=190 >> 19;
    // for k=0/31 the global boundary check stops expansion).
    const int gofs = below_total - nL;
    for (int lt = t; lt < nM; lt += 256) {
        const int li = nL + lt;
        const float xn = S[li];
        int l = li, r = li;
        #pragma unroll
        for (int st = 0; st < KNN - 1; ++st) {
            float pdl = -INFINITY, pdr = -INFINITY;
            if (l + gofs > 0) {
                const float xl = S[l - 1];
                pdl = 2.0f * xn * xl - xn * xn - xl * xl;   // reference pd formula
            }
            if (r + gofs < NPTS - 1) {
                const float xr = S[r + 1];
                pdr = 2.0f * xn * xr - xn * xn - xr * xr;
            }
            if (pdl >= pdr) --l; else ++r;
        }
        wmn[lt] = S[l];
        wmx[lt] = S[r];
    }
    __syncthreads();

    // ---------------- Phase D: folded conv+BN+relu, max & sum pooling --------
    const int c = lane;                        // channel = lane (c = t & 63)
    const float w0 = conv_w[2 * c];
    const float w1 = conv_w[2 * c + 1];
    const float sc = bn_g[c] / sqrtf(bn_v[c] + 1e-5f);
    const float A  = sc * w0;
    const float Bc = sc * (w1 - w0);
    const float bias = bn_b[c] - bn_m[c] * sc;

    float vmax = 0.0f, vsum = 0.0f;
    for (int lt = wv; lt < nM; lt += 4) {      // wave-uniform lt -> LDS broadcast
        const float xnv = S[nL + lt];
        const float wn  = wmn[lt];
        const float wx  = wmx[lt];
        const float ws  = (A >= 0.0f) ? wx : wn;   // relu+max monotonicity
        float h = fmaf(Bc, xnv, fmaf(A, ws, bias));
        h = fmaxf(h, 0.0f);
        vsum += h;
        vmax = fmaxf(vmax, h);
    }
    pmax[t] = vmax; psum[t] = vsum;
    __syncthreads();

    if (t < 64) {
        const float m  = fmaxf(fmaxf(pmax[t], pmax[t + 64]),
                               fmaxf(pmax[t + 128], pmax[t + 192]));
        const float su = psum[t] + psum[t + 64] + psum[t + 128] + psum[t + 192];
        partM[(b * 32 + k) * COUT + t] = m;
        partS[(b * 32 + k) * COUT + t] = su;
    }

    // ---------------- Phase E: publish partials, k==0 blocks reduce + head ---
    __threadfence();                           // release partials device-wide
    __syncthreads();                           // all stores issued before flag
    if (t == 0) atomicExch(&flag[b * 32 + k], (unsigned long long)SENT);

    if (k != 0) return;

    if (t < 32) {
        while (atomicAdd(&flag[b * 32 + t], 0ULL) != (unsigned long long)SENT)
            __builtin_amdgcn_s_sleep(8);
    }
    __syncthreads();
    __threadfence();                           // acquire others' partials

    if (t < 64) {
        float m = 0.0f, s = 0.0f;
        #pragma unroll 8
        for (int ch = 0; ch < 32; ++ch) {
            m = fmaxf(m, partM[(b * 32 + ch) * COUT + t]);
            s += partS[(b * 32 + ch) * COUT + t];
        }
        pool[t]        = m;
        pool[COUT + t] = s * (1.0f / (float)NPTS);
    }
    __syncthreads();
    if (t < NCLASS) {
        const float* lw = lin_w + t * (2 * COUT);
        float acc = 0.0f;
        #pragma unroll
        for (int cc = 0; cc < 2 * COUT; ++cc) acc += pool[cc] * lw[cc];
        out[b * NCLASS + t] = acc;
    }
}

extern "C" void kernel_launch(void* const* d_in, const int* in_sizes, int n_in,
                              void* d_out, int out_size, void* d_ws, size_t ws_size,
                              hipStream_t stream) {
    const float* x      = (const float*)d_in[0];   // (2, 8192)
    const float* conv_w = (const float*)d_in[1];   // (64, 2)
    const float* bn_g   = (const float*)d_in[2];
    const float* bn_b   = (const float*)d_in[3];
    const float* bn_m   = (const float*)d_in[4];
    const float* bn_v   = (const float*)d_in[5];
    const float* lin_w  = (const float*)d_in[6];   // (40, 128)
    float* out = (float*)d_out;                    // (2, 40) fp32

    // ws layout: flags (64 u64, 8B-aligned at base), then partials
    unsigned long long* flag = (unsigned long long*)d_ws;
    float* partM = (float*)(flag + BATCH * NBKT);  // 2*32*64
    float* partS = partM + BATCH * NBKT * COUT;    // 2*32*64

    fused_kernel<<<BATCH * NBKT, 256, 0, stream>>>(x, conv_w, bn_g, bn_b, bn_m,
                                                   bn_v, lin_w, partM, partS,
                                                   flag, out);
}